// Round 6
// baseline (136.703 us; speedup 1.0000x reference)
//
#include <hip/hip_runtime.h>

typedef unsigned short u16;
typedef u16 u16x8 __attribute__((ext_vector_type(8)));
typedef __bf16 bf16x8 __attribute__((ext_vector_type(8)));
typedef float f32x4 __attribute__((ext_vector_type(4)));

#define EMB 1024
#define TT 2048
#define BB 2
#define NHEADS 16
#define HD 64
#define MTOT (BB * TT)  // 4096

// ---------- helpers ----------
__device__ __forceinline__ u16 cvt(float f) {  // native f32->bf16 (RTNE)
  return __builtin_bit_cast(u16, (__bf16)f);
}

__device__ __forceinline__ bf16x8 asbf(u16x8 v) {
  return __builtin_bit_cast(bf16x8, v);
}

__device__ __forceinline__ void gload16(const void* g, void* l) {
  __builtin_amdgcn_global_load_lds(
      (const __attribute__((address_space(1))) void*)g,
      (__attribute__((address_space(3))) void*)l, 16, 0, 0);
}

// ---------- fused prep: x->bf16 + 4x W transpose->bf16, one launch ----------
__global__ __launch_bounds__(256) void k_prep(
    const float* __restrict__ x, u16* __restrict__ xb,
    const float* __restrict__ W0, const float* __restrict__ W1,
    const float* __restrict__ W2, const float* __restrict__ W3,
    u16* __restrict__ T0, u16* __restrict__ T1, u16* __restrict__ T2,
    u16* __restrict__ T3) {
  __shared__ float tile[32][33];
  const int bid = blockIdx.x;
  const int tid = threadIdx.x;
  if (bid >= 4096) {  // x conversion: 2048 blocks x 2048 elems
    int i = (bid - 4096) * 256 + tid;
    float4 a = ((const float4*)x)[i * 2];
    float4 b = ((const float4*)x)[i * 2 + 1];
    u16x8 o;
    o[0] = cvt(a.x); o[1] = cvt(a.y); o[2] = cvt(a.z); o[3] = cvt(a.w);
    o[4] = cvt(b.x); o[5] = cvt(b.y); o[6] = cvt(b.z); o[7] = cvt(b.w);
    ((u16x8*)xb)[i] = o;
    return;
  }
  const int z = bid >> 10;  // which W
  const float* __restrict__ W = (z == 0) ? W0 : (z == 1) ? W1 : (z == 2) ? W2 : W3;
  u16* __restrict__ Wt = (z == 0) ? T0 : (z == 1) ? T1 : (z == 2) ? T2 : T3;
  const int b = bid & 1023;
  const int bx = (b & 31) * 32, by = (b >> 5) * 32;
  const int tx = tid & 31;
  const int ty = tid >> 5;  // 0..7
#pragma unroll
  for (int r = ty; r < 32; r += 8) tile[r][tx] = W[(by + r) * EMB + bx + tx];
  __syncthreads();
#pragma unroll
  for (int r = ty; r < 32; r += 8)
    Wt[(bx + r) * EMB + by + tx] = cvt(tile[tx][r]);
}

// ---------- fused QKV GEMM (m97 structure, unchanged) ----------
__global__ __launch_bounds__(256) void k_gemm_qkv(
    const u16* __restrict__ xb, const u16* __restrict__ WqT,
    const u16* __restrict__ WkT, const u16* __restrict__ WvT,
    const float* __restrict__ bq, const float* __restrict__ bk,
    const float* __restrict__ bv, u16* __restrict__ Q, u16* __restrict__ K,
    u16* __restrict__ Vt) {
  __shared__ u16 Al[128 * 32];
  __shared__ u16 Bl[128 * 32];
  const int tid = threadIdx.x;
  const int lane = tid & 63;
  const int w = tid >> 6;
  const int wr = w >> 1, wc = w & 1;
  const int lr = lane & 15, lg = lane >> 4;
  const int m0 = blockIdx.x * 128;
  const int nb = blockIdx.y;           // 0..23
  const int seg = nb >> 3;             // 0=Q 1=K 2=V
  const int n0 = (nb & 7) * 128;
  const u16* __restrict__ Bt = (seg == 0) ? WqT : (seg == 1) ? WkT : WvT;
  const float* __restrict__ bias = (seg == 0) ? bq : (seg == 1) ? bk : bv;

  f32x4 acc[4][4];
#pragma unroll
  for (int i = 0; i < 4; i++)
#pragma unroll
    for (int j = 0; j < 4; j++) acc[i][j] = (f32x4){0.f, 0.f, 0.f, 0.f};

  const int srow = tid >> 2;           // 0..63
  const int scol = (tid & 3) * 8;
  const u16* ga0 = xb + (m0 + srow) * EMB + scol;
  const u16* gb0 = Bt + (n0 + srow) * EMB + scol;
  char* la0 = (char*)Al + w * 1024;    // wave-uniform LDS base
  char* lb0 = (char*)Bl + w * 1024;

  for (int k0 = 0; k0 < EMB; k0 += 32) {
    gload16(ga0 + k0, la0);
    gload16(ga0 + 64 * EMB + k0, la0 + 4096);
    gload16(gb0 + k0, lb0);
    gload16(gb0 + 64 * EMB + k0, lb0 + 4096);
    __syncthreads();
    u16x8 af[4], bfr[4];
#pragma unroll
    for (int mi = 0; mi < 4; mi++)
      af[mi] = *(const u16x8*)&Al[(wr * 64 + mi * 16 + lr) * 32 + lg * 8];
#pragma unroll
    for (int ni = 0; ni < 4; ni++)
      bfr[ni] = *(const u16x8*)&Bl[(wc * 64 + ni * 16 + lr) * 32 + lg * 8];
#pragma unroll
    for (int mi = 0; mi < 4; mi++)
#pragma unroll
      for (int ni = 0; ni < 4; ni++)
        acc[mi][ni] = __builtin_amdgcn_mfma_f32_16x16x32_bf16(
            asbf(af[mi]), asbf(bfr[ni]), acc[mi][ni], 0, 0, 0);
    __syncthreads();
  }

#pragma unroll
  for (int mi = 0; mi < 4; mi++) {
    const int lmb = wr * 64 + mi * 16 + lg * 4;
#pragma unroll
    for (int ni = 0; ni < 4; ni++) {
      const int ln = wc * 64 + ni * 16 + lr;
      const int n = n0 + ln;
      const float bv_ = bias[n];
      const int h = n >> 6, d = n & 63;
#pragma unroll
      for (int r = 0; r < 4; r++) {
        const int m = m0 + lmb + r;
        const int b = m >> 11, t = m & 2047;
        float v = acc[mi][ni][r] + bv_;
        if (seg == 0) {
          v *= 0.18033688011f;  // (1/sqrt(64)) * log2(e): exp2-domain scores
          Q[(((b * NHEADS + h) * TT) + t) * HD + d] = cvt(v);
        } else if (seg == 1) {
          K[(((b * NHEADS + h) * TT) + t) * HD + d] = cvt(v);
        } else {
          Vt[(((b * NHEADS + h) * HD) + d) * TT + t] = cvt(v);
        }
      }
    }
  }
}

// ---------- causal flash attention ----------
// Pairing (uniform 17 k128-tiles/block): waves 0-3 q-block hi, waves 4-7 lo.
// KVBLK=128, two-pass PV (P buffer stays 16x68). 2-phase double-buffered
// swizzled LDS staging via global_load_lds. Softmax in exp2 domain.
__global__ __launch_bounds__(512) void k_attn(const u16* __restrict__ Q,
                                              const u16* __restrict__ Kg,
                                              const u16* __restrict__ Vt,
                                              u16* __restrict__ AO) {
  __shared__ u16 Kl[2][128 * 64];  // 16KB x2: 128 k-rows x 128B (swizzled)
  __shared__ u16 Vl[2][64 * 128];  // 16KB x2: 64 d-rows x 256B (swizzled)
  __shared__ u16 Plds[8][16][68];  // per-wave P transpose (pad: 0-conflict)
  const int tid = threadIdx.x;
  const int lane = tid & 63;
  const int w = tid >> 6;          // 0..7
  const int lr = lane & 15, lg = lane >> 4;
  const int bh = blockIdx.x;       // 0..31
  const int pair = blockIdx.y;     // 0..15
  const int lo = pair, hi = 31 - pair;
  const int qblk = (w < 4) ? hi : lo;
  const int myend = qblk >> 1;     // this wave's last 128-col k-tile
  const int q0 = qblk * 64 + (w & 3) * 16;
  const u16* __restrict__ Qh = Q + bh * TT * HD;
  const u16* __restrict__ Kh = Kg + bh * TT * HD;
  const u16* __restrict__ Vh = Vt + bh * HD * TT;

  // staging maps (rule 21: linear LDS dest + pre-swizzled global source):
  // K: row h*64+(t>>3) (128B rows, 8 chunks), phys chunk t&7 holds global
  //    chunk (t&7)^(row&7).  V: row h*32+(t>>4) (256B rows, 16 chunks),
  //    phys chunk t&15 holds global chunk (t&15)^(row&7).
  const int krow = tid >> 3;                    // 0..63
  const int ksc = (tid & 7) ^ (krow & 7);
  const int vrow = tid >> 4;                    // 0..31
  const int vgc = (tid & 15) ^ (vrow & 7);

  u16x8 qf[2];
  qf[0] = *(const u16x8*)&Qh[(q0 + lr) * HD + lg * 8];
  qf[1] = *(const u16x8*)&Qh[(q0 + lr) * HD + 32 + lg * 8];

  f32x4 accO[4];
#pragma unroll
  for (int i = 0; i < 4; i++) accO[i] = (f32x4){0.f, 0.f, 0.f, 0.f};
  float mst[4] = {-__builtin_inff(), -__builtin_inff(), -__builtin_inff(),
                  -__builtin_inff()};
  float lsum[4] = {0.f, 0.f, 0.f, 0.f};  // per-lane partials (deferred sum)

  const int nkt = (hi >> 1) + 1;  // block-uniform loop count

  // prologue: stage k-tile 0 into buf 0
#pragma unroll
  for (int h = 0; h < 2; h++) {
    gload16(Kh + (h * 64 + krow) * HD + ksc * 8,
            (char*)Kl[0] + h * 8192 + w * 1024);
    gload16(Vh + (h * 32 + vrow) * TT + 0 + vgc * 8,
            (char*)Vl[0] + h * 8192 + w * 1024);
  }
  __syncthreads();  // drains vmcnt

  for (int kt = 0; kt < nkt; ++kt) {
    const int k0 = kt * 128;
    const int cur = kt & 1;
    if (kt + 1 < nkt) {  // issue next-tile loads BEFORE compute (2-phase)
      const int kn = k0 + 128;
#pragma unroll
      for (int h = 0; h < 2; h++) {
        gload16(Kh + (kn + h * 64 + krow) * HD + ksc * 8,
                (char*)Kl[cur ^ 1] + h * 8192 + w * 1024);
        gload16(Vh + (h * 32 + vrow) * TT + kn + vgc * 8,
                (char*)Vl[cur ^ 1] + h * 8192 + w * 1024);
      }
    }
    if (kt <= myend) {  // wave-uniform: lo-waves idle past their diagonal
      const char* Kc = (const char*)Kl[cur];
      const char* Vc = (const char*)Vl[cur];

      f32x4 s[8];
#pragma unroll
      for (int n = 0; n < 8; n++) s[n] = (f32x4){0.f, 0.f, 0.f, 0.f};
      __builtin_amdgcn_s_setprio(1);
#pragma unroll
      for (int n = 0; n < 8; n++) {
        const int row = n * 16 + lr;
#pragma unroll
        for (int dh = 0; dh < 2; dh++) {
          const int bo = ((dh * 4 + lg) ^ (lr & 7)) * 16;
          u16x8 kf = *(const u16x8*)(Kc + row * 128 + bo);
          s[n] = __builtin_amdgcn_mfma_f32_16x16x32_bf16(asbf(qf[dh]),
                                                         asbf(kf), s[n], 0, 0, 0);
        }
      }
      __builtin_amdgcn_s_setprio(0);
      if (kt == myend) {  // diagonal tile: causal mask
#pragma unroll
        for (int n = 0; n < 8; n++)
#pragma unroll
          for (int r = 0; r < 4; r++) {
            int col = k0 + n * 16 + lr, row = q0 + lg * 4 + r;
            if (col > row) s[n][r] = -__builtin_inff();
          }
      }
      // defer-max (log2 domain, THR=11): skip butterfly+rescale if small
      float lmax[4];
#pragma unroll
      for (int r = 0; r < 4; r++) {
        float a = fmaxf(fmaxf(s[0][r], s[1][r]), fmaxf(s[2][r], s[3][r]));
        float b = fmaxf(fmaxf(s[4][r], s[5][r]), fmaxf(s[6][r], s[7][r]));
        lmax[r] = fmaxf(a, b);
      }
      float g0 = fmaxf(lmax[0] - mst[0], lmax[1] - mst[1]);
      float g1 = fmaxf(lmax[2] - mst[2], lmax[3] - mst[3]);
      if (!__all(fmaxf(g0, g1) <= 11.0f)) {  // rare (always tile 0)
#pragma unroll
        for (int r = 0; r < 4; r++) {
          float rm = lmax[r];
          rm = fmaxf(rm, __shfl_xor(rm, 1, 16));
          rm = fmaxf(rm, __shfl_xor(rm, 2, 16));
          rm = fmaxf(rm, __shfl_xor(rm, 4, 16));
          rm = fmaxf(rm, __shfl_xor(rm, 8, 16));
          float mnew = fmaxf(mst[r], rm);
          float corr = exp2f(mst[r] - mnew);
          lsum[r] *= corr;
          mst[r] = mnew;
#pragma unroll
          for (int dt = 0; dt < 4; dt++) accO[dt][r] *= corr;
        }
      }
      // two PV passes over the 128 cols (P buffer reused in-wave)
#pragma unroll
      for (int p64 = 0; p64 < 2; p64++) {
#pragma unroll
        for (int r = 0; r < 4; r++) {
          float p0 = exp2f(s[p64 * 4 + 0][r] - mst[r]);
          float p1 = exp2f(s[p64 * 4 + 1][r] - mst[r]);
          float p2 = exp2f(s[p64 * 4 + 2][r] - mst[r]);
          float p3 = exp2f(s[p64 * 4 + 3][r] - mst[r]);
          lsum[r] += (p0 + p1) + (p2 + p3);
          const int row = lg * 4 + r;
          Plds[w][row][lr] = cvt(p0);
          Plds[w][row][16 + lr] = cvt(p1);
          Plds[w][row][32 + lr] = cvt(p2);
          Plds[w][row][48 + lr] = cvt(p3);
        }
        u16x8 pa0 = *(const u16x8*)&Plds[w][lr][lg * 8];
        u16x8 pa1 = *(const u16x8*)&Plds[w][lr][32 + lg * 8];
        __builtin_amdgcn_s_setprio(1);
#pragma unroll
        for (int dt = 0; dt < 4; dt++) {
          const int row = dt * 16 + lr;
          const int bo0 = p64 * 128 + ((lg ^ (lr & 7)) * 16);
          const int bo1 = p64 * 128 + (((4 + lg) ^ (lr & 7)) * 16);
          u16x8 vf0 = *(const u16x8*)(Vc + row * 256 + bo0);
          u16x8 vf1 = *(const u16x8*)(Vc + row * 256 + bo1);
          accO[dt] = __builtin_amdgcn_mfma_f32_16x16x32_bf16(
              asbf(pa0), asbf(vf0), accO[dt], 0, 0, 0);
          accO[dt] = __builtin_amdgcn_mfma_f32_16x16x32_bf16(
              asbf(pa1), asbf(vf1), accO[dt], 0, 0, 0);
        }
        __builtin_amdgcn_s_setprio(0);
      }
    }
    __syncthreads();  // drains vmcnt: next buf staged; cur free to overwrite
  }
  // final row-sum butterfly + epilogue -> AO [B][T][EMB] bf16
  float rinv[4];
#pragma unroll
  for (int r = 0; r < 4; r++) {
    float t = lsum[r];
    t += __shfl_xor(t, 1, 16);
    t += __shfl_xor(t, 2, 16);
    t += __shfl_xor(t, 4, 16);
    t += __shfl_xor(t, 8, 16);
    rinv[r] = 1.0f / t;
  }
  const int b = bh >> 4, h = bh & 15;
#pragma unroll
  for (int dt = 0; dt < 4; dt++)
#pragma unroll
    for (int r = 0; r < 4; r++) {
      const int row = q0 + lg * 4 + r;
      const int d = h * 64 + dt * 16 + lr;
      AO[(b * TT + row) * EMB + d] = cvt(accO[dt][r] * rinv[r]);
    }
}

// ---------- output projection GEMM (fp32 out + bias) ----------
__global__ __launch_bounds__(256) void k_gemm_out(const u16* __restrict__ AO,
                                                  const u16* __restrict__ WoT,
                                                  const float* __restrict__ bo,
                                                  float* __restrict__ out) {
  __shared__ u16 Al[128 * 32];
  __shared__ u16 Bl[128 * 32];
  const int tid = threadIdx.x;
  const int lane = tid & 63;
  const int w = tid >> 6;
  const int wr = w >> 1, wc = w & 1;
  const int lr = lane & 15, lg = lane >> 4;
  const int m0 = blockIdx.x * 128;
  const int n0 = blockIdx.y * 128;

  f32x4 acc[4][4];
#pragma unroll
  for (int i = 0; i < 4; i++)
#pragma unroll
    for (int j = 0; j < 4; j++) acc[i][j] = (f32x4){0.f, 0.f, 0.f, 0.f};

  const int srow = tid >> 2;
  const int scol = (tid & 3) * 8;
  const u16* ga0 = AO + (m0 + srow) * EMB + scol;
  const u16* gb0 = WoT + (n0 + srow) * EMB + scol;
  char* la0 = (char*)Al + w * 1024;
  char* lb0 = (char*)Bl + w * 1024;

  for (int k0 = 0; k0 < EMB; k0 += 32) {
    gload16(ga0 + k0, la0);
    gload16(ga0 + 64 * EMB + k0, la0 + 4096);
    gload16(gb0 + k0, lb0);
    gload16(gb0 + 64 * EMB + k0, lb0 + 4096);
    __syncthreads();
    u16x8 af[4], bfr[4];
#pragma unroll
    for (int mi = 0; mi < 4; mi++)
      af[mi] = *(const u16x8*)&Al[(wr * 64 + mi * 16 + lr) * 32 + lg * 8];
#pragma unroll
    for (int ni = 0; ni < 4; ni++)
      bfr[ni] = *(const u16x8*)&Bl[(wc * 64 + ni * 16 + lr) * 32 + lg * 8];
#pragma unroll
    for (int mi = 0; mi < 4; mi++)
#pragma unroll
      for (int ni = 0; ni < 4; ni++)
        acc[mi][ni] = __builtin_amdgcn_mfma_f32_16x16x32_bf16(
            asbf(af[mi]), asbf(bfr[ni]), acc[mi][ni], 0, 0, 0);
    __syncthreads();
  }

#pragma unroll
  for (int mi = 0; mi < 4; mi++) {
    const int lmb = wr * 64 + mi * 16 + lg * 4;
#pragma unroll
    for (int ni = 0; ni < 4; ni++) {
      const int ln = wc * 64 + ni * 16 + lr;
      const int n = n0 + ln;
      const float bv_ = bo[n];
#pragma unroll
      for (int r = 0; r < 4; r++) {
        const int m = m0 + lmb + r;
        out[m * EMB + n] = acc[mi][ni][r] + bv_;
      }
    }
  }
}

// ---------- launch ----------
extern "C" void kernel_launch(void* const* d_in, const int* in_sizes, int n_in,
                              void* d_out, int out_size, void* d_ws,
                              size_t ws_size, hipStream_t stream) {
  const float* x = (const float*)d_in[0];
  const float* Wq = (const float*)d_in[1];
  const float* bq = (const float*)d_in[2];
  const float* Wk = (const float*)d_in[3];
  const float* bk = (const float*)d_in[4];
  const float* Wv = (const float*)d_in[5];
  const float* bv = (const float*)d_in[6];
  const float* Wo = (const float*)d_in[7];
  const float* bo = (const float*)d_in[8];
  float* out = (float*)d_out;

  char* ws = (char*)d_ws;
  u16* xb = (u16*)ws;                      // 8 MB (reused as AO)
  u16* WqT = (u16*)(ws + (8u << 20));      // 2 MB
  u16* WkT = (u16*)(ws + (10u << 20));     // 2 MB
  u16* WvT = (u16*)(ws + (12u << 20));     // 2 MB
  u16* WoT = (u16*)(ws + (14u << 20));     // 2 MB
  u16* Qb = (u16*)(ws + (16u << 20));      // 8 MB
  u16* Kb = (u16*)(ws + (24u << 20));      // 8 MB
  u16* Vtb = (u16*)(ws + (32u << 20));     // 8 MB (total 40 MB)
  u16* AO = xb;

  k_prep<<<6144, 256, 0, stream>>>(x, xb, Wq, Wk, Wv, Wo, WqT, WkT, WvT, WoT);
  k_gemm_qkv<<<dim3(32, 24), 256, 0, stream>>>(xb, WqT, WkT, WvT, bq, bk, bv,
                                               Qb, Kb, Vtb);
  k_attn<<<dim3(32, 16), 512, 0, stream>>>(Qb, Kb, Vtb, AO);
  k_gemm_out<<<dim3(32, 8), 256, 0, stream>>>(AO, WoT, bo, out);
}

// Round 7
// 136.419 us; speedup vs baseline: 1.0021x; 1.0021x over previous
//
#include <hip/hip_runtime.h>

typedef unsigned short u16;
typedef u16 u16x8 __attribute__((ext_vector_type(8)));
typedef __bf16 bf16x8 __attribute__((ext_vector_type(8)));
typedef float f32x4 __attribute__((ext_vector_type(4)));

#define EMB 1024
#define TT 2048
#define BB 2
#define NHEADS 16
#define HD 64
#define MTOT (BB * TT)  // 4096

// ---------- helpers ----------
__device__ __forceinline__ u16 cvt(float f) {  // native f32->bf16 (RTNE)
  return __builtin_bit_cast(u16, (__bf16)f);
}

__device__ __forceinline__ bf16x8 asbf(u16x8 v) {
  return __builtin_bit_cast(bf16x8, v);
}

__device__ __forceinline__ void gload16(const void* g, void* l) {
  __builtin_amdgcn_global_load_lds(
      (const __attribute__((address_space(1))) void*)g,
      (__attribute__((address_space(3))) void*)l, 16, 0, 0);
}

// ---------- fused prep: x->bf16 + 4x W transpose->bf16, one launch ----------
__global__ __launch_bounds__(256) void k_prep(
    const float* __restrict__ x, u16* __restrict__ xb,
    const float* __restrict__ W0, const float* __restrict__ W1,
    const float* __restrict__ W2, const float* __restrict__ W3,
    u16* __restrict__ T0, u16* __restrict__ T1, u16* __restrict__ T2,
    u16* __restrict__ T3) {
  __shared__ float tile[32][33];
  const int bid = blockIdx.x;
  const int tid = threadIdx.x;
  if (bid >= 4096) {  // x conversion: 2048 blocks x 2048 elems
    int i = (bid - 4096) * 256 + tid;
    float4 a = ((const float4*)x)[i * 2];
    float4 b = ((const float4*)x)[i * 2 + 1];
    u16x8 o;
    o[0] = cvt(a.x); o[1] = cvt(a.y); o[2] = cvt(a.z); o[3] = cvt(a.w);
    o[4] = cvt(b.x); o[5] = cvt(b.y); o[6] = cvt(b.z); o[7] = cvt(b.w);
    ((u16x8*)xb)[i] = o;
    return;
  }
  const int z = bid >> 10;  // which W
  const float* __restrict__ W = (z == 0) ? W0 : (z == 1) ? W1 : (z == 2) ? W2 : W3;
  u16* __restrict__ Wt = (z == 0) ? T0 : (z == 1) ? T1 : (z == 2) ? T2 : T3;
  const int b = bid & 1023;
  const int bx = (b & 31) * 32, by = (b >> 5) * 32;
  const int tx = tid & 31;
  const int ty = tid >> 5;  // 0..7
#pragma unroll
  for (int r = ty; r < 32; r += 8) tile[r][tx] = W[(by + r) * EMB + bx + tx];
  __syncthreads();
#pragma unroll
  for (int r = ty; r < 32; r += 8)
    Wt[(bx + r) * EMB + by + tx] = cvt(tile[tx][r]);
}

// ---------- fused QKV GEMM (m97 structure + XCD swizzle) ----------
__global__ __launch_bounds__(256) void k_gemm_qkv(
    const u16* __restrict__ xb, const u16* __restrict__ WqT,
    const u16* __restrict__ WkT, const u16* __restrict__ WvT,
    const float* __restrict__ bq, const float* __restrict__ bk,
    const float* __restrict__ bv, u16* __restrict__ Q, u16* __restrict__ K,
    u16* __restrict__ Vt) {
  __shared__ u16 Al[128 * 32];
  __shared__ u16 Bl[128 * 32];
  const int tid = threadIdx.x;
  const int lane = tid & 63;
  const int w = tid >> 6;
  const int wr = w >> 1, wc = w & 1;
  const int lr = lane & 15, lg = lane >> 4;
  // XCD swizzle (T1): nwg=768=8*96 exactly; each XCD gets 3 contiguous
  // B-panels (nb) across all m-blocks -> B L2-resident, A panel reused.
  const int wg = blockIdx.y * 32 + blockIdx.x;  // HW dispatch-linear id
  const int swz = (wg & 7) * 96 + (wg >> 3);    // bijective remap
  const int m0 = (swz & 31) * 128;
  const int nb = swz >> 5;             // 0..23
  const int seg = nb >> 3;             // 0=Q 1=K 2=V
  const int n0 = (nb & 7) * 128;
  const u16* __restrict__ Bt = (seg == 0) ? WqT : (seg == 1) ? WkT : WvT;
  const float* __restrict__ bias = (seg == 0) ? bq : (seg == 1) ? bk : bv;

  f32x4 acc[4][4];
#pragma unroll
  for (int i = 0; i < 4; i++)
#pragma unroll
    for (int j = 0; j < 4; j++) acc[i][j] = (f32x4){0.f, 0.f, 0.f, 0.f};

  const int srow = tid >> 2;           // 0..63
  const int scol = (tid & 3) * 8;
  const u16* ga0 = xb + (m0 + srow) * EMB + scol;
  const u16* gb0 = Bt + (n0 + srow) * EMB + scol;
  char* la0 = (char*)Al + w * 1024;    // wave-uniform LDS base
  char* lb0 = (char*)Bl + w * 1024;

  for (int k0 = 0; k0 < EMB; k0 += 32) {
    gload16(ga0 + k0, la0);
    gload16(ga0 + 64 * EMB + k0, la0 + 4096);
    gload16(gb0 + k0, lb0);
    gload16(gb0 + 64 * EMB + k0, lb0 + 4096);
    __syncthreads();
    u16x8 af[4], bfr[4];
#pragma unroll
    for (int mi = 0; mi < 4; mi++)
      af[mi] = *(const u16x8*)&Al[(wr * 64 + mi * 16 + lr) * 32 + lg * 8];
#pragma unroll
    for (int ni = 0; ni < 4; ni++)
      bfr[ni] = *(const u16x8*)&Bl[(wc * 64 + ni * 16 + lr) * 32 + lg * 8];
#pragma unroll
    for (int mi = 0; mi < 4; mi++)
#pragma unroll
      for (int ni = 0; ni < 4; ni++)
        acc[mi][ni] = __builtin_amdgcn_mfma_f32_16x16x32_bf16(
            asbf(af[mi]), asbf(bfr[ni]), acc[mi][ni], 0, 0, 0);
    __syncthreads();
  }

#pragma unroll
  for (int mi = 0; mi < 4; mi++) {
    const int lmb = wr * 64 + mi * 16 + lg * 4;
#pragma unroll
    for (int ni = 0; ni < 4; ni++) {
      const int ln = wc * 64 + ni * 16 + lr;
      const int n = n0 + ln;
      const float bv_ = bias[n];
      const int h = n >> 6, d = n & 63;
#pragma unroll
      for (int r = 0; r < 4; r++) {
        const int m = m0 + lmb + r;
        const int b = m >> 11, t = m & 2047;
        float v = acc[mi][ni][r] + bv_;
        if (seg == 0) {
          v *= 0.18033688011f;  // (1/sqrt(64)) * log2(e): exp2-domain scores
          Q[(((b * NHEADS + h) * TT) + t) * HD + d] = cvt(v);
        } else if (seg == 1) {
          K[(((b * NHEADS + h) * TT) + t) * HD + d] = cvt(v);
        } else {
          Vt[(((b * NHEADS + h) * HD) + d) * TT + t] = cvt(v);
        }
      }
    }
  }
}

// ---------- causal flash attention (round-5 geometry: KVBLK=64) ----------
// Uniform-work pairing: waves 0-3 q-block hi=31-pair, waves 4-7 lo=pair;
// every block does exactly 33 tile-computes. Grid 32x16 = 512 blocks = 2/CU,
// LDS 50KB -> 3 blocks/CU. 2-phase double-buffered swizzled LDS staging.
// Softmax in exp2 domain with defer-max (THR=11 bits).
__global__ __launch_bounds__(512) void k_attn(const u16* __restrict__ Q,
                                              const u16* __restrict__ Kg,
                                              const u16* __restrict__ Vt,
                                              u16* __restrict__ AO) {
  __shared__ u16 Kl[2][64 * 64];   // 8KB x2
  __shared__ u16 Vl[2][64 * 64];   // 8KB x2
  __shared__ u16 Plds[8][16][68];  // per-wave P transpose (pad: 0-conflict)
  const int tid = threadIdx.x;
  const int lane = tid & 63;
  const int w = tid >> 6;          // 0..7
  const int lr = lane & 15, lg = lane >> 4;
  const int bh = blockIdx.x;       // 0..31
  const int pair = blockIdx.y;     // 0..15
  const int lo = pair, hi = 31 - pair;
  const int qblk = (w < 4) ? hi : lo;      // this wave's q-block
  const int myend = qblk;                  // last k-tile index for this wave
  const int q0 = qblk * 64 + (w & 3) * 16;
  const u16* __restrict__ Qh = Q + bh * TT * HD;
  const u16* __restrict__ Kh = Kg + bh * TT * HD;
  const u16* __restrict__ Vh = Vt + bh * HD * TT;

  // staging: 512 threads cover a full 64x128B tile; thread t = row t>>3,
  // chunk t&7. Linear LDS dest (wave base w*1024 + lane*16) + pre-swizzled
  // global source chunk sc = c ^ (row&7); reads apply the same XOR.
  const int srow = tid >> 3;               // 0..63
  const int sc = (tid & 7) ^ (srow & 7);

  u16x8 qf[2];
  qf[0] = *(const u16x8*)&Qh[(q0 + lr) * HD + lg * 8];
  qf[1] = *(const u16x8*)&Qh[(q0 + lr) * HD + 32 + lg * 8];

  f32x4 accO[4];
#pragma unroll
  for (int i = 0; i < 4; i++) accO[i] = (f32x4){0.f, 0.f, 0.f, 0.f};
  float mst[4] = {-__builtin_inff(), -__builtin_inff(), -__builtin_inff(),
                  -__builtin_inff()};
  float lsum[4] = {0.f, 0.f, 0.f, 0.f};  // per-lane partials (deferred sum)

  const int nkt = hi + 1;  // block-uniform loop count

  // prologue: stage tile 0 into buf 0 (one gload16 per thread per matrix)
  gload16(Kh + srow * HD + sc * 8, (char*)Kl[0] + w * 1024);
  gload16(Vh + srow * TT + 0 + sc * 8, (char*)Vl[0] + w * 1024);
  __syncthreads();  // drains vmcnt

  for (int kt = 0; kt < nkt; ++kt) {
    const int k0 = kt * 64;
    const int cur = kt & 1;
    if (kt + 1 < nkt) {  // issue next-tile loads BEFORE compute (2-phase)
      const int kn = k0 + 64;
      gload16(Kh + (kn + srow) * HD + sc * 8, (char*)Kl[cur ^ 1] + w * 1024);
      gload16(Vh + srow * TT + kn + sc * 8, (char*)Vl[cur ^ 1] + w * 1024);
    }
    if (kt <= myend) {  // wave-uniform: lo-waves idle past their diagonal
      const char* Kc = (const char*)Kl[cur];
      const char* Vc = (const char*)Vl[cur];

      f32x4 s[4];
#pragma unroll
      for (int n = 0; n < 4; n++) s[n] = (f32x4){0.f, 0.f, 0.f, 0.f};
      __builtin_amdgcn_s_setprio(1);
#pragma unroll
      for (int n = 0; n < 4; n++) {
        const int row = n * 16 + lr;
#pragma unroll
        for (int dh = 0; dh < 2; dh++) {
          const int bo = (dh * 64 + lg * 16) ^ ((row & 7) << 4);
          u16x8 kf = *(const u16x8*)(Kc + row * 128 + bo);
          s[n] = __builtin_amdgcn_mfma_f32_16x16x32_bf16(asbf(qf[dh]),
                                                         asbf(kf), s[n], 0, 0, 0);
        }
      }
      __builtin_amdgcn_s_setprio(0);
      if (kt == myend) {  // diagonal tile: causal mask
#pragma unroll
        for (int n = 0; n < 4; n++)
#pragma unroll
          for (int r = 0; r < 4; r++) {
            int col = k0 + n * 16 + lr, row = q0 + lg * 4 + r;
            if (col > row) s[n][r] = -__builtin_inff();
          }
      }
      // defer-max (log2 domain, THR=11): skip butterfly+rescale if small
      float lmax[4];
#pragma unroll
      for (int r = 0; r < 4; r++)
        lmax[r] = fmaxf(fmaxf(s[0][r], s[1][r]), fmaxf(s[2][r], s[3][r]));
      float g0 = fmaxf(lmax[0] - mst[0], lmax[1] - mst[1]);
      float g1 = fmaxf(lmax[2] - mst[2], lmax[3] - mst[3]);
      if (!__all(fmaxf(g0, g1) <= 11.0f)) {  // rare path (always tile 0)
#pragma unroll
        for (int r = 0; r < 4; r++) {
          float rm = lmax[r];
          rm = fmaxf(rm, __shfl_xor(rm, 1, 16));
          rm = fmaxf(rm, __shfl_xor(rm, 2, 16));
          rm = fmaxf(rm, __shfl_xor(rm, 4, 16));
          rm = fmaxf(rm, __shfl_xor(rm, 8, 16));
          float mnew = fmaxf(mst[r], rm);
          float corr = exp2f(mst[r] - mnew);
          lsum[r] *= corr;
          mst[r] = mnew;
#pragma unroll
          for (int dt = 0; dt < 4; dt++) accO[dt][r] *= corr;
        }
      }
#pragma unroll
      for (int r = 0; r < 4; r++) {
        float p0 = exp2f(s[0][r] - mst[r]);
        float p1 = exp2f(s[1][r] - mst[r]);
        float p2 = exp2f(s[2][r] - mst[r]);
        float p3 = exp2f(s[3][r] - mst[r]);
        lsum[r] += (p0 + p1) + (p2 + p3);
        const int row = lg * 4 + r;
        Plds[w][row][lr] = cvt(p0);
        Plds[w][row][16 + lr] = cvt(p1);
        Plds[w][row][32 + lr] = cvt(p2);
        Plds[w][row][48 + lr] = cvt(p3);
      }
      // PV: A = P (16x64) via LDS transpose; B = V rows from swizzled LDS
      u16x8 pa0 = *(const u16x8*)&Plds[w][lr][lg * 8];
      u16x8 pa1 = *(const u16x8*)&Plds[w][lr][32 + lg * 8];
      __builtin_amdgcn_s_setprio(1);
#pragma unroll
      for (int dt = 0; dt < 4; dt++) {
        const int row = dt * 16 + lr;
        const int bo0 = (lg * 16) ^ ((row & 7) << 4);
        const int bo1 = (64 + lg * 16) ^ ((row & 7) << 4);
        u16x8 vf0 = *(const u16x8*)(Vc + row * 128 + bo0);
        u16x8 vf1 = *(const u16x8*)(Vc + row * 128 + bo1);
        accO[dt] = __builtin_amdgcn_mfma_f32_16x16x32_bf16(asbf(pa0),
                                                           asbf(vf0), accO[dt], 0, 0, 0);
        accO[dt] = __builtin_amdgcn_mfma_f32_16x16x32_bf16(asbf(pa1),
                                                           asbf(vf1), accO[dt], 0, 0, 0);
      }
      __builtin_amdgcn_s_setprio(0);
    }
    __syncthreads();  // drains vmcnt: next buf staged; cur free to overwrite
  }
  // final row-sum butterfly + epilogue -> AO [B][T][EMB] bf16
  float rinv[4];
#pragma unroll
  for (int r = 0; r < 4; r++) {
    float t = lsum[r];
    t += __shfl_xor(t, 1, 16);
    t += __shfl_xor(t, 2, 16);
    t += __shfl_xor(t, 4, 16);
    t += __shfl_xor(t, 8, 16);
    rinv[r] = 1.0f / t;
  }
  const int b = bh >> 4, h = bh & 15;
#pragma unroll
  for (int dt = 0; dt < 4; dt++)
#pragma unroll
    for (int r = 0; r < 4; r++) {
      const int row = q0 + lg * 4 + r;
      const int d = h * 64 + dt * 16 + lr;
      AO[(b * TT + row) * EMB + d] = cvt(accO[dt][r] * rinv[r]);
    }
}

// ---------- output projection GEMM (fp32 out + bias, XCD swizzle) ----------
__global__ __launch_bounds__(256) void k_gemm_out(const u16* __restrict__ AO,
                                                  const u16* __restrict__ WoT,
                                                  const float* __restrict__ bo,
                                                  float* __restrict__ out) {
  __shared__ u16 Al[128 * 32];
  __shared__ u16 Bl[128 * 32];
  const int tid = threadIdx.x;
  const int lane = tid & 63;
  const int w = tid >> 6;
  const int wr = w >> 1, wc = w & 1;
  const int lr = lane & 15, lg = lane >> 4;
  // XCD swizzle: nwg=256=8*32; each XCD gets one contiguous B-panel.
  const int wg = blockIdx.y * 32 + blockIdx.x;
  const int swz = (wg & 7) * 32 + (wg >> 3);
  const int m0 = (swz & 31) * 128;
  const int n0 = (swz >> 5) * 128;

  f32x4 acc[4][4];
#pragma unroll
  for (int i = 0; i < 4; i++)
#pragma unroll
    for (int j = 0; j < 4; j++) acc[i][j] = (f32x4){0.f, 0.f, 0.f, 0.f};

  const int srow = tid >> 2;
  const int scol = (tid & 3) * 8;
  const u16* ga0 = AO + (m0 + srow) * EMB + scol;
  const u16* gb0 = WoT + (n0 + srow) * EMB + scol;
  char* la0 = (char*)Al + w * 1024;
  char* lb0 = (char*)Bl + w * 1024;

  for (int k0 = 0; k0 < EMB; k0 += 32) {
    gload16(ga0 + k0, la0);
    gload16(ga0 + 64 * EMB + k0, la0 + 4096);
    gload16(gb0 + k0, lb0);
    gload16(gb0 + 64 * EMB + k0, lb0 + 4096);
    __syncthreads();
    u16x8 af[4], bfr[4];
#pragma unroll
    for (int mi = 0; mi < 4; mi++)
      af[mi] = *(const u16x8*)&Al[(wr * 64 + mi * 16 + lr) * 32 + lg * 8];
#pragma unroll
    for (int ni = 0; ni < 4; ni++)
      bfr[ni] = *(const u16x8*)&Bl[(wc * 64 + ni * 16 + lr) * 32 + lg * 8];
#pragma unroll
    for (int mi = 0; mi < 4; mi++)
#pragma unroll
      for (int ni = 0; ni < 4; ni++)
        acc[mi][ni] = __builtin_amdgcn_mfma_f32_16x16x32_bf16(
            asbf(af[mi]), asbf(bfr[ni]), acc[mi][ni], 0, 0, 0);
    __syncthreads();
  }

#pragma unroll
  for (int mi = 0; mi < 4; mi++) {
    const int lmb = wr * 64 + mi * 16 + lg * 4;
#pragma unroll
    for (int ni = 0; ni < 4; ni++) {
      const int ln = wc * 64 + ni * 16 + lr;
      const int n = n0 + ln;
      const float bv_ = bo[n];
#pragma unroll
      for (int r = 0; r < 4; r++) {
        const int m = m0 + lmb + r;
        out[m * EMB + n] = acc[mi][ni][r] + bv_;
      }
    }
  }
}

// ---------- launch ----------
extern "C" void kernel_launch(void* const* d_in, const int* in_sizes, int n_in,
                              void* d_out, int out_size, void* d_ws,
                              size_t ws_size, hipStream_t stream) {
  const float* x = (const float*)d_in[0];
  const float* Wq = (const float*)d_in[1];
  const float* bq = (const float*)d_in[2];
  const float* Wk = (const float*)d_in[3];
  const float* bk = (const float*)d_in[4];
  const float* Wv = (const float*)d_in[5];
  const float* bv = (const float*)d_in[6];
  const float* Wo = (const float*)d_in[7];
  const float* bo = (const float*)d_in[8];
  float* out = (float*)d_out;

  char* ws = (char*)d_ws;
  u16* xb = (u16*)ws;                      // 8 MB (reused as AO)
  u16* WqT = (u16*)(ws + (8u << 20));      // 2 MB
  u16* WkT = (u16*)(ws + (10u << 20));     // 2 MB
  u16* WvT = (u16*)(ws + (12u << 20));     // 2 MB
  u16* WoT = (u16*)(ws + (14u << 20));     // 2 MB
  u16* Qb = (u16*)(ws + (16u << 20));      // 8 MB
  u16* Kb = (u16*)(ws + (24u << 20));      // 8 MB
  u16* Vtb = (u16*)(ws + (32u << 20));     // 8 MB (total 40 MB)
  u16* AO = xb;

  k_prep<<<6144, 256, 0, stream>>>(x, xb, Wq, Wk, Wv, Wo, WqT, WkT, WvT, WoT);
  k_gemm_qkv<<<dim3(32, 24), 256, 0, stream>>>(xb, WqT, WkT, WvT, bq, bk, bv,
                                               Qb, Kb, Vtb);
  k_attn<<<dim3(32, 16), 512, 0, stream>>>(Qb, Kb, Vtb, AO);
  k_gemm_out<<<dim3(32, 8), 256, 0, stream>>>(AO, WoT, bo, out);
}

// Round 8
// 114.701 us; speedup vs baseline: 1.1918x; 1.1893x over previous
//
#include <hip/hip_runtime.h>

typedef unsigned short u16;
typedef u16 u16x8 __attribute__((ext_vector_type(8)));
typedef __bf16 bf16x8 __attribute__((ext_vector_type(8)));
typedef float f32x4 __attribute__((ext_vector_type(4)));

#define EMB 1024
#define TT 2048
#define BB 2
#define NHEADS 16
#define HD 64
#define MTOT (BB * TT)  // 4096

// ---------- helpers ----------
__device__ __forceinline__ u16 cvt(float f) {  // native f32->bf16 (RTNE)
  return __builtin_bit_cast(u16, (__bf16)f);
}

__device__ __forceinline__ bf16x8 asbf(u16x8 v) {
  return __builtin_bit_cast(bf16x8, v);
}

__device__ __forceinline__ void gload16(const void* g, void* l) {
  __builtin_amdgcn_global_load_lds(
      (const __attribute__((address_space(1))) void*)g,
      (__attribute__((address_space(3))) void*)l, 16, 0, 0);
}

// ---------- fused prep: x->bf16 + 4x W transpose->bf16, one launch ----------
__global__ __launch_bounds__(256) void k_prep(
    const float* __restrict__ x, u16* __restrict__ xb,
    const float* __restrict__ W0, const float* __restrict__ W1,
    const float* __restrict__ W2, const float* __restrict__ W3,
    u16* __restrict__ T0, u16* __restrict__ T1, u16* __restrict__ T2,
    u16* __restrict__ T3) {
  __shared__ float tile[32][33];
  const int bid = blockIdx.x;
  const int tid = threadIdx.x;
  if (bid >= 4096) {  // x conversion: 2048 blocks x 2048 elems
    int i = (bid - 4096) * 256 + tid;
    float4 a = ((const float4*)x)[i * 2];
    float4 b = ((const float4*)x)[i * 2 + 1];
    u16x8 o;
    o[0] = cvt(a.x); o[1] = cvt(a.y); o[2] = cvt(a.z); o[3] = cvt(a.w);
    o[4] = cvt(b.x); o[5] = cvt(b.y); o[6] = cvt(b.z); o[7] = cvt(b.w);
    ((u16x8*)xb)[i] = o;
    return;
  }
  const int z = bid >> 10;  // which W
  const float* __restrict__ W = (z == 0) ? W0 : (z == 1) ? W1 : (z == 2) ? W2 : W3;
  u16* __restrict__ Wt = (z == 0) ? T0 : (z == 1) ? T1 : (z == 2) ? T2 : T3;
  const int b = bid & 1023;
  const int bx = (b & 31) * 32, by = (b >> 5) * 32;
  const int tx = tid & 31;
  const int ty = tid >> 5;  // 0..7
#pragma unroll
  for (int r = ty; r < 32; r += 8) tile[r][tx] = W[(by + r) * EMB + bx + tx];
  __syncthreads();
#pragma unroll
  for (int r = ty; r < 32; r += 8)
    Wt[(bx + r) * EMB + by + tx] = cvt(tile[tx][r]);
}

// ---------- fused QKV GEMM (m97 structure; default block mapping) ----------
__global__ __launch_bounds__(256) void k_gemm_qkv(
    const u16* __restrict__ xb, const u16* __restrict__ WqT,
    const u16* __restrict__ WkT, const u16* __restrict__ WvT,
    const float* __restrict__ bq, const float* __restrict__ bk,
    const float* __restrict__ bv, u16* __restrict__ Q, u16* __restrict__ K,
    u16* __restrict__ Vt) {
  __shared__ u16 Al[128 * 32];
  __shared__ u16 Bl[128 * 32];
  const int tid = threadIdx.x;
  const int lane = tid & 63;
  const int w = tid >> 6;
  const int wr = w >> 1, wc = w & 1;
  const int lr = lane & 15, lg = lane >> 4;
  // default mapping: round-robin XCDs over m (m%8==XCD) -> A panel (1MB)
  // L2-resident per XCD; B panels L3-shared. (r7 custom swizzle regressed.)
  const int m0 = blockIdx.x * 128;
  const int nb = blockIdx.y;           // 0..23
  const int seg = nb >> 3;             // 0=Q 1=K 2=V
  const int n0 = (nb & 7) * 128;
  const u16* __restrict__ Bt = (seg == 0) ? WqT : (seg == 1) ? WkT : WvT;
  const float* __restrict__ bias = (seg == 0) ? bq : (seg == 1) ? bk : bv;

  f32x4 acc[4][4];
#pragma unroll
  for (int i = 0; i < 4; i++)
#pragma unroll
    for (int j = 0; j < 4; j++) acc[i][j] = (f32x4){0.f, 0.f, 0.f, 0.f};

  const int srow = tid >> 2;           // 0..63
  const int scol = (tid & 3) * 8;
  const u16* ga0 = xb + (m0 + srow) * EMB + scol;
  const u16* gb0 = Bt + (n0 + srow) * EMB + scol;
  char* la0 = (char*)Al + w * 1024;    // wave-uniform LDS base
  char* lb0 = (char*)Bl + w * 1024;

  for (int k0 = 0; k0 < EMB; k0 += 32) {
    gload16(ga0 + k0, la0);
    gload16(ga0 + 64 * EMB + k0, la0 + 4096);
    gload16(gb0 + k0, lb0);
    gload16(gb0 + 64 * EMB + k0, lb0 + 4096);
    __syncthreads();
    u16x8 af[4], bfr[4];
#pragma unroll
    for (int mi = 0; mi < 4; mi++)
      af[mi] = *(const u16x8*)&Al[(wr * 64 + mi * 16 + lr) * 32 + lg * 8];
#pragma unroll
    for (int ni = 0; ni < 4; ni++)
      bfr[ni] = *(const u16x8*)&Bl[(wc * 64 + ni * 16 + lr) * 32 + lg * 8];
#pragma unroll
    for (int mi = 0; mi < 4; mi++)
#pragma unroll
      for (int ni = 0; ni < 4; ni++)
        acc[mi][ni] = __builtin_amdgcn_mfma_f32_16x16x32_bf16(
            asbf(af[mi]), asbf(bfr[ni]), acc[mi][ni], 0, 0, 0);
    __syncthreads();
  }

#pragma unroll
  for (int mi = 0; mi < 4; mi++) {
    const int lmb = wr * 64 + mi * 16 + lg * 4;
#pragma unroll
    for (int ni = 0; ni < 4; ni++) {
      const int ln = wc * 64 + ni * 16 + lr;
      const int n = n0 + ln;
      const float bv_ = bias[n];
      const int h = n >> 6, d = n & 63;
#pragma unroll
      for (int r = 0; r < 4; r++) {
        const int m = m0 + lmb + r;
        const int b = m >> 11, t = m & 2047;
        float v = acc[mi][ni][r] + bv_;
        if (seg == 0) {
          v *= 0.18033688011f;  // (1/sqrt(64)) * log2(e): exp2-domain scores
          Q[(((b * NHEADS + h) * TT) + t) * HD + d] = cvt(v);
        } else if (seg == 1) {
          K[(((b * NHEADS + h) * TT) + t) * HD + d] = cvt(v);
        } else {
          Vt[(((b * NHEADS + h) * HD) + d) * TT + t] = cvt(v);
        }
      }
    }
  }
}

// ---------- causal flash attention ----------
// Swapped QK^T (S^T = mfma(K,Q)): each lane owns ONE q-row (q0+lr); the K-row
// permutation kr = (lr&3)+4(n&1)+8(lr>>2)+32(n>>1) makes each lane's 16 score
// cols exactly the PV A-frag slots {8lg..8lg+7}+{32+8lg..} -> P stays in
// registers (no LDS round-trip, no butterflies on the common path).
// LDS swizzle g(row) = (row&3)|(((row>>3)&1)<<2) (8 slots -> 2-way = free).
// Pairing: waves 0-3 q-block hi=31-pair, 4-7 lo=pair; uniform 33 tiles/block.
__global__ __launch_bounds__(512) void k_attn(const u16* __restrict__ Q,
                                              const u16* __restrict__ Kg,
                                              const u16* __restrict__ Vt,
                                              u16* __restrict__ AO) {
  __shared__ u16 Kl[2][64 * 64];   // 8KB x2
  __shared__ u16 Vl[2][64 * 64];   // 8KB x2
  const int tid = threadIdx.x;
  const int lane = tid & 63;
  const int w = tid >> 6;          // 0..7
  const int lr = lane & 15, lg = lane >> 4;
  const int bh = blockIdx.x;       // 0..31
  const int pair = blockIdx.y;     // 0..15
  const int lo = pair, hi = 31 - pair;
  const int qblk = (w < 4) ? hi : lo;      // this wave's q-block
  const int myend = qblk;                  // last k-tile index for this wave
  const int q0 = qblk * 64 + (w & 3) * 16;
  const u16* __restrict__ Qh = Q + bh * TT * HD;
  const u16* __restrict__ Kh = Kg + bh * TT * HD;
  const u16* __restrict__ Vh = Vt + bh * HD * TT;

  // staging: thread t covers row t>>3, phys chunk t&7 of the 64x128B tile.
  // Pre-swizzled global source chunk sc = (t&7) ^ g(row).
  const int srow = tid >> 3;  // 0..63
  const int sgz = ((tid >> 3) & 3) | (((tid >> 6) & 1) << 2);  // g(srow)
  const int sc = (tid & 7) ^ sgz;

  u16x8 qf[2];
  qf[0] = *(const u16x8*)&Qh[(q0 + lr) * HD + lg * 8];
  qf[1] = *(const u16x8*)&Qh[(q0 + lr) * HD + 32 + lg * 8];

  f32x4 accO[4];
#pragma unroll
  for (int i = 0; i < 4; i++) accO[i] = (f32x4){0.f, 0.f, 0.f, 0.f};
  float mst = -__builtin_inff();  // per-lane: running max of row q0+lr
  float lsum = 0.f;               // per-lane partial denominator

  const int nkt = hi + 1;  // block-uniform loop count

  gload16(Kh + srow * HD + sc * 8, (char*)Kl[0] + w * 1024);
  gload16(Vh + srow * TT + sc * 8, (char*)Vl[0] + w * 1024);
  __syncthreads();  // drains vmcnt

  for (int kt = 0; kt < nkt; ++kt) {
    const int k0 = kt * 64;
    const int cur = kt & 1;
    if (kt + 1 < nkt) {  // issue next-tile loads BEFORE compute (2-phase)
      const int kn = k0 + 64;
      gload16(Kh + (kn + srow) * HD + sc * 8, (char*)Kl[cur ^ 1] + w * 1024);
      gload16(Vh + srow * TT + kn + sc * 8, (char*)Vl[cur ^ 1] + w * 1024);
    }
    if (kt <= myend) {  // wave-uniform: lo-waves idle past their diagonal
      const char* Kc = (const char*)Kl[cur];
      const char* Vc = (const char*)Vl[cur];

      f32x4 s[4];
#pragma unroll
      for (int n = 0; n < 4; n++) s[n] = (f32x4){0.f, 0.f, 0.f, 0.f};
      __builtin_amdgcn_s_setprio(1);
#pragma unroll
      for (int n = 0; n < 4; n++) {
        // permuted K-row for MFMA block n (see header comment)
        const int kr =
            (lr & 3) + ((n & 1) << 2) + ((lr >> 2) << 3) + ((n >> 1) << 5);
        const int gg = (kr & 3) | (((kr >> 3) & 1) << 2);
#pragma unroll
        for (int dh = 0; dh < 2; dh++) {
          const int bo = ((dh * 4 + lg) ^ gg) << 4;
          u16x8 kf = *(const u16x8*)(Kc + kr * 128 + bo);
          s[n] = __builtin_amdgcn_mfma_f32_16x16x32_bf16(asbf(kf), asbf(qf[dh]),
                                                         s[n], 0, 0, 0);
        }
      }
      __builtin_amdgcn_s_setprio(0);
      if (kt == myend) {  // diagonal tile: causal mask (col > my q-row)
        const int rowq = q0 + lr;
#pragma unroll
        for (int n = 0; n < 4; n++) {
          const int cb = k0 + ((n & 1) << 2) + (lg << 3) + ((n >> 1) << 5);
#pragma unroll
          for (int r = 0; r < 4; r++)
            if (cb + r > rowq) s[n][r] = -__builtin_inff();
        }
      }
      // lane-local row max over this tile's 16 cols
      float m01 = fmaxf(fmaxf(s[0][0], s[0][1]), fmaxf(s[0][2], s[0][3]));
      float m1 = fmaxf(fmaxf(s[1][0], s[1][1]), fmaxf(s[1][2], s[1][3]));
      float m2 = fmaxf(fmaxf(s[2][0], s[2][1]), fmaxf(s[2][2], s[2][3]));
      float m3 = fmaxf(fmaxf(s[3][0], s[3][1]), fmaxf(s[3][2], s[3][3]));
      float lmax = fmaxf(fmaxf(m01, m1), fmaxf(m2, m3));
      // defer-max (log2 domain, THR=11 bits). NaN on tile0 forces rescale.
      if (!__all(lmax - mst <= 11.0f)) {
        float rm = lmax;
        rm = fmaxf(rm, __shfl_xor(rm, 16));
        rm = fmaxf(rm, __shfl_xor(rm, 32));
        float mnew = fmaxf(mst, rm);
        float corr = exp2f(mst - mnew);
        lsum *= corr;
        mst = mnew;
#pragma unroll
        for (int r = 0; r < 4; r++) {  // corr for accO's q-row (lg*4+r)
          float ca = __shfl(corr, 20 * lg + r);
#pragma unroll
          for (int dt = 0; dt < 4; dt++) accO[dt][r] *= ca;
        }
      }
      // P in-register: p[n][r] are exactly PV A-frag slots
      float p[4][4];
      float ls = 0.f;
#pragma unroll
      for (int n = 0; n < 4; n++)
#pragma unroll
        for (int r = 0; r < 4; r++) {
          p[n][r] = exp2f(s[n][r] - mst);
          ls += p[n][r];
        }
      lsum += ls;
      u16x8 a1, a2;
#pragma unroll
      for (int r = 0; r < 4; r++) {
        a1[r] = cvt(p[0][r]);
        a1[4 + r] = cvt(p[1][r]);
        a2[r] = cvt(p[2][r]);
        a2[4 + r] = cvt(p[3][r]);
      }
      __builtin_amdgcn_s_setprio(1);
#pragma unroll
      for (int dt = 0; dt < 4; dt++) {
        const int row = dt * 16 + lr;
        const int gg = (row & 3) | (((row >> 3) & 1) << 2);
        const int bo0 = ((lg ^ gg) << 4);
        const int bo1 = (((4 + lg) ^ gg) << 4);
        u16x8 vf0 = *(const u16x8*)(Vc + row * 128 + bo0);
        u16x8 vf1 = *(const u16x8*)(Vc + row * 128 + bo1);
        accO[dt] = __builtin_amdgcn_mfma_f32_16x16x32_bf16(asbf(a1), asbf(vf0),
                                                           accO[dt], 0, 0, 0);
        accO[dt] = __builtin_amdgcn_mfma_f32_16x16x32_bf16(asbf(a2), asbf(vf1),
                                                           accO[dt], 0, 0, 0);
      }
      __builtin_amdgcn_s_setprio(0);
    }
    __syncthreads();  // drains vmcnt: next buf staged; cur free to overwrite
  }
  // denominator: reduce the 4 lanes sharing this q-row, then redistribute
  float t = lsum;
  t += __shfl_xor(t, 16);
  t += __shfl_xor(t, 32);
  float rinv = 1.0f / t;
  float ra[4];
#pragma unroll
  for (int r = 0; r < 4; r++) ra[r] = __shfl(rinv, 20 * lg + r);
  const int b = bh >> 4, h = bh & 15;
#pragma unroll
  for (int dt = 0; dt < 4; dt++)
#pragma unroll
    for (int r = 0; r < 4; r++) {
      const int row = q0 + lg * 4 + r;
      const int d = h * 64 + dt * 16 + lr;
      AO[(b * TT + row) * EMB + d] = cvt(accO[dt][r] * ra[r]);
    }
}

// ---------- output projection GEMM (fp32 out + bias) ----------
__global__ __launch_bounds__(256) void k_gemm_out(const u16* __restrict__ AO,
                                                  const u16* __restrict__ WoT,
                                                  const float* __restrict__ bo,
                                                  float* __restrict__ out) {
  __shared__ u16 Al[128 * 32];
  __shared__ u16 Bl[128 * 32];
  const int tid = threadIdx.x;
  const int lane = tid & 63;
  const int w = tid >> 6;
  const int wr = w >> 1, wc = w & 1;
  const int lr = lane & 15, lg = lane >> 4;
  const int m0 = blockIdx.x * 128;
  const int n0 = blockIdx.y * 128;

  f32x4 acc[4][4];
#pragma unroll
  for (int i = 0; i < 4; i++)
#pragma unroll
    for (int j = 0; j < 4; j++) acc[i][j] = (f32x4){0.f, 0.f, 0.f, 0.f};

  const int srow = tid >> 2;
  const int scol = (tid & 3) * 8;
  const u16* ga0 = AO + (m0 + srow) * EMB + scol;
  const u16* gb0 = WoT + (n0 + srow) * EMB + scol;
  char* la0 = (char*)Al + w * 1024;
  char* lb0 = (char*)Bl + w * 1024;

  for (int k0 = 0; k0 < EMB; k0 += 32) {
    gload16(ga0 + k0, la0);
    gload16(ga0 + 64 * EMB + k0, la0 + 4096);
    gload16(gb0 + k0, lb0);
    gload16(gb0 + 64 * EMB + k0, lb0 + 4096);
    __syncthreads();
    u16x8 af[4], bfr[4];
#pragma unroll
    for (int mi = 0; mi < 4; mi++)
      af[mi] = *(const u16x8*)&Al[(wr * 64 + mi * 16 + lr) * 32 + lg * 8];
#pragma unroll
    for (int ni = 0; ni < 4; ni++)
      bfr[ni] = *(const u16x8*)&Bl[(wc * 64 + ni * 16 + lr) * 32 + lg * 8];
#pragma unroll
    for (int mi = 0; mi < 4; mi++)
#pragma unroll
      for (int ni = 0; ni < 4; ni++)
        acc[mi][ni] = __builtin_amdgcn_mfma_f32_16x16x32_bf16(
            asbf(af[mi]), asbf(bfr[ni]), acc[mi][ni], 0, 0, 0);
    __syncthreads();
  }

#pragma unroll
  for (int mi = 0; mi < 4; mi++) {
    const int lmb = wr * 64 + mi * 16 + lg * 4;
#pragma unroll
    for (int ni = 0; ni < 4; ni++) {
      const int ln = wc * 64 + ni * 16 + lr;
      const int n = n0 + ln;
      const float bv_ = bo[n];
#pragma unroll
      for (int r = 0; r < 4; r++) {
        const int m = m0 + lmb + r;
        out[m * EMB + n] = acc[mi][ni][r] + bv_;
      }
    }
  }
}

// ---------- launch ----------
extern "C" void kernel_launch(void* const* d_in, const int* in_sizes, int n_in,
                              void* d_out, int out_size, void* d_ws,
                              size_t ws_size, hipStream_t stream) {
  const float* x = (const float*)d_in[0];
  const float* Wq = (const float*)d_in[1];
  const float* bq = (const float*)d_in[2];
  const float* Wk = (const float*)d_in[3];
  const float* bk = (const float*)d_in[4];
  const float* Wv = (const float*)d_in[5];
  const float* bv = (const float*)d_in[6];
  const float* Wo = (const float*)d_in[7];
  const float* bo = (const float*)d_in[8];
  float* out = (float*)d_out;

  char* ws = (char*)d_ws;
  u16* xb = (u16*)ws;                      // 8 MB (reused as AO)
  u16* WqT = (u16*)(ws + (8u << 20));      // 2 MB
  u16* WkT = (u16*)(ws + (10u << 20));     // 2 MB
  u16* WvT = (u16*)(ws + (12u << 20));     // 2 MB
  u16* WoT = (u16*)(ws + (14u << 20));     // 2 MB
  u16* Qb = (u16*)(ws + (16u << 20));      // 8 MB
  u16* Kb = (u16*)(ws + (24u << 20));      // 8 MB
  u16* Vtb = (u16*)(ws + (32u << 20));     // 8 MB (total 40 MB)
  u16* AO = xb;

  k_prep<<<6144, 256, 0, stream>>>(x, xb, Wq, Wk, Wv, Wo, WqT, WkT, WvT, WoT);
  k_gemm_qkv<<<dim3(32, 24), 256, 0, stream>>>(xb, WqT, WkT, WvT, bq, bk, bv,
                                               Qb, Kb, Vtb);
  k_attn<<<dim3(32, 16), 512, 0, stream>>>(Qb, Kb, Vtb, AO);
  k_gemm_out<<<dim3(32, 8), 256, 0, stream>>>(AO, WoT, bo, out);
}